// Round 1
// baseline (396.048 us; speedup 1.0000x reference)
//
#include <hip/hip_runtime.h>

// Problem constants (from reference)
constexpr int B    = 16384;
constexpr int F    = 30;
constexpr int BINS = 30;
constexpr int EMB  = 100;
constexpr float T  = 0.5f;
constexpr int PAIRS = B * F;           // 491520
constexpr int BLOCK = 256;             // 491520 / 256 = 1920 exact

__global__ __launch_bounds__(BLOCK) void ad_embed_kernel(
    const float* __restrict__ x,   // [B*F]  (B,1,F) flat
    const float* __restrict__ W1,  // [BINS] (BINS,1) flat
    const float* __restrict__ Wl,  // [BINS*BINS] row-major (o,i)
    const float* __restrict__ W2,  // [EMB*BINS]  row-major (o,i)
    float* __restrict__ out)       // [PAIRS*EMB]
{
    __shared__ float sW1[BINS];
    __shared__ float sWl[BINS][BINS];
    __shared__ float sW2[EMB][BINS];

    const int tid = threadIdx.x;

    // Cooperative weight staging (tiny: 15.7 KB)
    for (int i = tid; i < BINS; i += BLOCK) sW1[i] = W1[i];
    for (int i = tid; i < BINS * BINS; i += BLOCK) sWl[i / BINS][i % BINS] = Wl[i];
    for (int i = tid; i < EMB * BINS; i += BLOCK) sW2[i / BINS][i % BINS] = W2[i];
    __syncthreads();

    const int pair = blockIdx.x * BLOCK + tid;   // grid is exact, no guard needed
    const float xv = x[pair];                    // coalesced 4B/lane

    // y_i = leaky_relu(x * W1[i])   (leaky slope 0.01: max(v, 0.01v))
    float y[BINS];
#pragma unroll
    for (int i = 0; i < BINS; ++i) {
        float v = xv * sW1[i];
        y[i] = fmaxf(v, 0.01f * v);
    }

    // z_o = (sum_i y_i * Wl[o,i] + 0.1*y_o) * T ; track max for softmax
    float z[BINS];
    float m = -INFINITY;
#pragma unroll
    for (int o = 0; o < BINS; ++o) {
        float acc = 0.1f * y[o];
#pragma unroll
        for (int i = 0; i < BINS; ++i)
            acc = fmaf(y[i], sWl[o][i], acc);   // uniform LDS read -> broadcast
        float zo = acc * T;
        z[o] = zo;
        m = fmaxf(m, zo);
    }

    // softmax over 30 bins
    float sum = 0.f;
#pragma unroll
    for (int o = 0; o < BINS; ++o) {
        float e = __expf(z[o] - m);
        z[o] = e;
        sum += e;
    }
    const float inv = 1.0f / sum;
#pragma unroll
    for (int o = 0; o < BINS; ++o) z[o] *= inv;

    // out_o = sum_i p_i * W2[o,i], o in [0,100); write float4 (per-thread contiguous 400B)
    float* op = out + (size_t)pair * EMB;
    for (int o = 0; o < EMB; o += 4) {          // rolled x25 to bound code size
        float a0 = 0.f, a1 = 0.f, a2 = 0.f, a3 = 0.f;
#pragma unroll
        for (int i = 0; i < BINS; ++i) {
            const float p = z[i];
            a0 = fmaf(p, sW2[o + 0][i], a0);
            a1 = fmaf(p, sW2[o + 1][i], a1);
            a2 = fmaf(p, sW2[o + 2][i], a2);
            a3 = fmaf(p, sW2[o + 3][i], a3);
        }
        float4 r; r.x = a0; r.y = a1; r.z = a2; r.w = a3;
        *reinterpret_cast<float4*>(op + o) = r;
    }
}

extern "C" void kernel_launch(void* const* d_in, const int* in_sizes, int n_in,
                              void* d_out, int out_size, void* d_ws, size_t ws_size,
                              hipStream_t stream) {
    const float* x  = (const float*)d_in[0];
    const float* W1 = (const float*)d_in[1];
    const float* Wl = (const float*)d_in[2];
    const float* W2 = (const float*)d_in[3];
    float* out = (float*)d_out;

    dim3 grid(PAIRS / BLOCK);   // 1920
    dim3 block(BLOCK);
    ad_embed_kernel<<<grid, block, 0, stream>>>(x, W1, Wl, W2, out);
}